// Round 2
// baseline (85.330 us; speedup 1.0000x reference)
//
#include <hip/hip_runtime.h>
#include <hip/hip_bf16.h>

// Problem constants (N,C,H,W) = (32,256,56,56), GROUPS=8
#define NN 32
#define CC 256
#define HW 3136            // H*W
#define HW4 784            // HW/4 float4 per (n,c) plane
#define CHW 802816         // C*H*W
#define CHW4 200704        // C*H*W/4
#define NCHW 25690112      // total elements
#define GROUPS 8
#define CPG 32             // C/GROUPS
#define NHW 100352         // N*H*W  (per-channel count)
#define GHW 100352         // CPG*HW (per-group count)
#define EPSF 1e-5f
#define CHUNKS 13          // ceil(HW4/64) 64-float4 chunks per plane
#define NB1 (NN*CHUNKS)    // 416 blocks for fused stats

// ---- kernel 1: ONE pass over x ->
//      S1p/S2p[(n*13+chunk)*256 + c]  (per-(n,c,chunk) plane-sum partials)
//      pT2[block]                     (partial sum of (sum_c x)^2 over positions)
__global__ __launch_bounds__(256) void fused_stats_kernel(
    const float4* __restrict__ x4,
    float* __restrict__ S1p, float* __restrict__ S2p, float* __restrict__ pT2)
{
    const int b = blockIdx.x;
    const int n = b / CHUNKS;
    const int chunk = b % CHUNKS;
    const int tid = threadIdx.x;
    const int wave = tid >> 6;
    const int lane = tid & 63;
    const int p4 = chunk * 64 + lane;          // float4 position in plane
    const bool pvalid = p4 < HW4;              // last chunk: only 16 valid lanes

    __shared__ float sh_s1[4][64];             // [wave][k]  (c = wave + 4k)
    __shared__ float sh_s2[4][64];
    __shared__ float4 sh_T[4][64];             // per-wave cross-channel sums per lane

    const float4* base = x4 + (size_t)n * CHW4 + p4;
    float4 T = make_float4(0.f, 0.f, 0.f, 0.f);

    // wave w handles channels c = w + 4k; 64 consecutive f4 per wave load.
    #pragma unroll 8
    for (int k = 0; k < 64; ++k) {
        const int c = wave + (k << 2);
        float t = 0.f, q = 0.f;
        if (pvalid) {
            float4 v = base[(size_t)c * HW4];
            T.x += v.x; T.y += v.y; T.z += v.z; T.w += v.w;
            t = v.x + v.y + v.z + v.w;
            q = v.x*v.x + v.y*v.y + v.z*v.z + v.w*v.w;
        }
        #pragma unroll
        for (int off = 32; off; off >>= 1) {
            t += __shfl_down(t, off, 64);
            q += __shfl_down(q, off, 64);
        }
        if (lane == 0) { sh_s1[wave][k] = t; sh_s2[wave][k] = q; }
    }
    sh_T[wave][lane] = T;
    __syncthreads();

    // coalesced store of per-(block, c) partials: c = (tid&3) + 4*(tid>>2)
    S1p[b * 256 + tid] = sh_s1[tid & 3][tid >> 2];
    S2p[b * 256 + tid] = sh_s2[tid & 3][tid >> 2];

    // combine T across the 4 waves, square, reduce -> pT2[b]
    if (tid < 64) {
        float4 Ta = sh_T[0][tid], Tb = sh_T[1][tid], Tc = sh_T[2][tid], Td = sh_T[3][tid];
        const float tx = Ta.x + Tb.x + Tc.x + Td.x;
        const float ty = Ta.y + Tb.y + Tc.y + Td.y;
        const float tz = Ta.z + Tb.z + Tc.z + Td.z;
        const float tw = Ta.w + Tb.w + Tc.w + Td.w;
        float t2 = tx*tx + ty*ty + tz*tz + tw*tw;
        #pragma unroll
        for (int off = 32; off; off >>= 1) t2 += __shfl_down(t2, off, 64);
        if (tid == 0) pT2[b] = t2;
    }
}

// ---- kernel 2: fold the 13 chunk partials -> S1/S2[n*256+c] --------------
__global__ __launch_bounds__(256) void reduce_s_kernel(
    const float* __restrict__ S1p, const float* __restrict__ S2p,
    float* __restrict__ S1, float* __restrict__ S2)
{
    const int n = blockIdx.x, c = threadIdx.x;
    float a = 0.f, b = 0.f;
    #pragma unroll
    for (int ch = 0; ch < CHUNKS; ++ch) {
        a += S1p[(n * CHUNKS + ch) * 256 + c];
        b += S2p[(n * CHUNKS + ch) * 256 + c];
    }
    S1[n * 256 + c] = a;
    S2[n * 256 + c] = b;
}

// ---- kernel 3: all stats -> gates -> per-(n,c) affine coeffs A,B ---------
__global__ __launch_bounds__(256) void finalize_kernel(
    const float* __restrict__ S1, const float* __restrict__ S2,
    const float* __restrict__ partialT2,
    const float* __restrict__ weight, const float* __restrict__ bias,
    const float* __restrict__ gate_logits, const float* __restrict__ diag_proj,
    float* __restrict__ A, float* __restrict__ B)
{
    const int tid = threadIdx.x;
    __shared__ float sh_mu_b[CC], sh_rs_b[CC];
    __shared__ float sh_mu_g[NN * GROUPS], sh_rs_g[NN * GROUPS];
    __shared__ float sh_mu_l[NN], sh_rs_l[NN];
    __shared__ float sh_red1[4], sh_red2[4], sh_red3[4], sh_red4[4];
    __shared__ float sh_gate[3];

    const float inv_NHW  = 1.f / (float)NHW;
    const float inv_CHW  = 1.f / (float)CHW;
    const float inv_GHW  = 1.f / (float)GHW;
    const float inv_NCHW = 1.f / (float)NCHW;

    // ---- BN: per-channel stats (thread = channel) ----
    const int c = tid;
    float s1 = 0.f, s2 = 0.f;
    for (int n = 0; n < NN; ++n) { s1 += S1[n * CC + c]; s2 += S2[n * CC + c]; }
    const float mu_b  = s1 * inv_NHW;
    const float var_b = s2 * inv_NHW - mu_b * mu_b;
    sh_mu_b[c] = mu_b;
    sh_rs_b[c] = rsqrtf(var_b + EPSF);

    // ---- GN: per-(n,g) stats (thread = n*8+g) ----
    const int ng_n = tid >> 3, ng_g = tid & 7;
    float s1g = 0.f, s2g = 0.f;
    for (int cc = 0; cc < CPG; ++cc) {
        const int idx = ng_n * CC + ng_g * CPG + cc;
        s1g += S1[idx]; s2g += S2[idx];
    }
    const float mu_g  = s1g * inv_GHW;
    const float var_g = s2g * inv_GHW - mu_g * mu_g;
    sh_mu_g[tid] = mu_g;
    sh_rs_g[tid] = rsqrtf(var_g + EPSF);

    // ---- LN: reduce GN sums over the 8 groups of each sample ----
    float s1l = s1g, s2l = s2g;
    #pragma unroll
    for (int off = 1; off < 8; off <<= 1) {
        s1l += __shfl_xor(s1l, off, 64);
        s2l += __shfl_xor(s2l, off, 64);
    }
    float var_l_contrib = 0.f;
    if (ng_g == 0) {
        const float mu_l  = s1l * inv_CHW;
        const float var_l = s2l * inv_CHW - mu_l * mu_l;
        sh_mu_l[ng_n] = mu_l;
        sh_rs_l[ng_n] = rsqrtf(var_l + EPSF);
        var_l_contrib = var_l;
    }

    // ---- T^2 partials for channel_var ----
    float t2p = 0.f;
    for (int i = tid; i < NB1; i += 256) t2p += partialT2[i];

    // ---- combined block reductions ----
    float r1 = var_b, r2 = s2, r3 = var_l_contrib, r4 = t2p;
    #pragma unroll
    for (int off = 32; off; off >>= 1) {
        r1 += __shfl_down(r1, off, 64);
        r2 += __shfl_down(r2, off, 64);
        r3 += __shfl_down(r3, off, 64);
        r4 += __shfl_down(r4, off, 64);
    }
    const int wave = tid >> 6, lane = tid & 63;
    if (lane == 0) { sh_red1[wave] = r1; sh_red2[wave] = r2; sh_red3[wave] = r3; sh_red4[wave] = r4; }
    __syncthreads();
    if (tid == 0) {
        const float sum_var_b = sh_red1[0] + sh_red1[1] + sh_red1[2] + sh_red1[3];
        const float total_x2  = sh_red2[0] + sh_red2[1] + sh_red2[2] + sh_red2[3];
        const float sum_var_l = sh_red3[0] + sh_red3[1] + sh_red3[2] + sh_red3[3];
        const float sum_T2    = sh_red4[0] + sh_red4[1] + sh_red4[2] + sh_red4[3];

        const float batch_var   = sum_var_b * (1.f / (float)CC);
        const float sample_var  = sum_var_l * (1.f / (float)NN);
        const float channel_var = total_x2 * inv_NCHW
                                - sum_T2 * inv_NHW * (1.f / ((float)CC * (float)CC));

        float desc[3];
        desc[0] = tanhf(logf(fmaxf(batch_var,   EPSF)));
        desc[1] = tanhf(logf(fmaxf(sample_var,  EPSF)));
        desc[2] = tanhf(logf(fmaxf(channel_var, EPSF)));

        float lg[3];
        #pragma unroll
        for (int i = 0; i < 3; ++i) {
            lg[i] = gate_logits[i] + diag_proj[i*3+0]*desc[0]
                                   + diag_proj[i*3+1]*desc[1]
                                   + diag_proj[i*3+2]*desc[2];
        }
        const float m = fmaxf(lg[0], fmaxf(lg[1], lg[2]));
        const float e0 = expf(lg[0]-m), e1 = expf(lg[1]-m), e2 = expf(lg[2]-m);
        const float inv = 1.f / (e0 + e1 + e2);
        sh_gate[0] = e0 * inv; sh_gate[1] = e1 * inv; sh_gate[2] = e2 * inv;
    }
    __syncthreads();

    // ---- per-(n,c) affine coefficients ----
    const float g0 = sh_gate[0], g1 = sh_gate[1], g2 = sh_gate[2];
    for (int i = tid; i < NN * CC; i += 256) {
        const int n = i >> 8, ch = i & 255, g = ch >> 5;
        const float w = weight[ch], bi = bias[ch];
        const float rb = sh_rs_b[ch], rl = sh_rs_l[n], rg = sh_rs_g[n*8+g];
        const float mb = sh_mu_b[ch], ml = sh_mu_l[n], mg = sh_mu_g[n*8+g];
        const float scale = g0*rb + g1*rl + g2*rg;
        const float offs  = g0*mb*rb + g1*ml*rl + g2*mg*rg;
        A[i] = w * scale;
        B[i] = bi - w * offs;
    }
}

// ---- kernel 4: y = x*A[nc] + B[nc], one block per (n,c) plane ------------
__global__ __launch_bounds__(256) void apply_kernel(
    const float4* __restrict__ x4, const float* __restrict__ A,
    const float* __restrict__ B, float4* __restrict__ y4)
{
    const int nc = blockIdx.x;
    const float a = A[nc], b = B[nc];
    const float4* xp = x4 + (size_t)nc * HW4;
    float4* yp = y4 + (size_t)nc * HW4;
    for (int i = threadIdx.x; i < HW4; i += 256) {
        float4 v = xp[i];
        v.x = fmaf(v.x, a, b);
        v.y = fmaf(v.y, a, b);
        v.z = fmaf(v.z, a, b);
        v.w = fmaf(v.w, a, b);
        yp[i] = v;
    }
}

extern "C" void kernel_launch(void* const* d_in, const int* in_sizes, int n_in,
                              void* d_out, int out_size, void* d_ws, size_t ws_size,
                              hipStream_t stream) {
    const float* x           = (const float*)d_in[0];
    const float* weight      = (const float*)d_in[1];
    const float* bias        = (const float*)d_in[2];
    const float* gate_logits = (const float*)d_in[3];
    const float* diag_proj   = (const float*)d_in[4];
    float* out = (float*)d_out;

    float* ws  = (float*)d_ws;
    float* S1p = ws;                 // 416*256 = 106496
    float* S2p = ws + 106496;        // 106496
    float* S1  = ws + 212992;        // 8192
    float* S2  = ws + 221184;        // 8192
    float* A   = ws + 229376;        // 8192
    float* B   = ws + 237568;        // 8192
    float* pT2 = ws + 245760;        // 416

    fused_stats_kernel<<<NB1, 256, 0, stream>>>((const float4*)x, S1p, S2p, pT2);
    reduce_s_kernel<<<NN, 256, 0, stream>>>(S1p, S2p, S1, S2);
    finalize_kernel<<<1, 256, 0, stream>>>(S1, S2, pT2, weight, bias,
                                           gate_logits, diag_proj, A, B);
    apply_kernel<<<NN * CC, 256, 0, stream>>>((const float4*)x, A, B, (float4*)out);
}

// Round 3
// 77.275 us; speedup vs baseline: 1.1042x; 1.1042x over previous
//
#include <hip/hip_runtime.h>
#include <hip/hip_bf16.h>

// Problem constants (N,C,H,W) = (32,256,56,56), GROUPS=8
#define NN 32
#define CC 256
#define HW 3136            // H*W
#define HW4 784            // HW/4 float4 per (n,c) plane
#define CHW 802816         // C*H*W
#define CHW4 200704        // C*H*W/4
#define NCHW 25690112      // total elements
#define GROUPS 8
#define CPG 32             // C/GROUPS
#define NHW 100352         // N*H*W  (per-channel count)
#define GHW 100352         // CPG*HW (per-group count)
#define EPSF 1e-5f
#define PCHUNK 13          // ceil(HW/256) position chunks (scalar positions)
#define NPT2 (NN*PCHUNK)   // 416 T^2 partials
#define CGS 2              // channel groups for chansum
#define CPB 128            // channels per chansum block (CC/CGS)

// ---- kernel 1: per-(n,c) plane sums. One wave = one full plane. ----------
// grid = NN*64 blocks; block b covers channels [4b .. 4b+3] (nc = b*4+wave).
__global__ __launch_bounds__(256) void plane_stats_kernel(
    const float4* __restrict__ x4, float* __restrict__ S1, float* __restrict__ S2)
{
    const int wave = threadIdx.x >> 6, lane = threadIdx.x & 63;
    const int nc = blockIdx.x * 4 + wave;
    const float4* p = x4 + (size_t)nc * HW4;
    float s1 = 0.f, s2 = 0.f;
    #pragma unroll 4
    for (int i = lane; i < HW4; i += 64) {
        float4 v = p[i];
        s1 += v.x + v.y + v.z + v.w;
        s2 += v.x*v.x + v.y*v.y + v.z*v.z + v.w*v.w;
    }
    #pragma unroll
    for (int off = 32; off; off >>= 1) {
        s1 += __shfl_down(s1, off, 64);
        s2 += __shfl_down(s2, off, 64);
    }
    if (lane == 0) { S1[nc] = s1; S2[nc] = s2; }
}

// ---- kernel 2: partial cross-channel sums T over CPB channels ------------
// grid = CGS*NN*PCHUNK blocks; thread = scalar position; no reductions.
__global__ __launch_bounds__(256) void chansum_kernel(
    const float* __restrict__ x, float* __restrict__ pT)
{
    const int b = blockIdx.x;                 // ((cg*NN + n)*PCHUNK + chunk)
    const int chunk = b % PCHUNK;
    const int nc = b / PCHUNK;
    const int n = nc % NN;
    const int cg = nc / NN;
    const int pos = chunk * 256 + threadIdx.x;
    float T = 0.f;
    if (pos < HW) {
        const float* p = x + (size_t)n * CHW + (size_t)cg * CPB * HW + pos;
        #pragma unroll 16
        for (int c = 0; c < CPB; ++c) T += p[(size_t)c * HW];
    }
    pT[b * 256 + threadIdx.x] = (pos < HW) ? T : 0.f;
}

// ---- kernel 3: combine channel-group partials, square, reduce -> pT2 -----
// grid = NN*PCHUNK = 416 blocks.
__global__ __launch_bounds__(256) void combine_kernel(
    const float* __restrict__ pT, float* __restrict__ pT2)
{
    const int b = blockIdx.x;                 // n*PCHUNK + chunk
    const int tid = threadIdx.x;
    const float T = pT[b * 256 + tid] + pT[NN * PCHUNK * 256 + b * 256 + tid];
    float t2 = T * T;                          // invalid positions wrote 0
    #pragma unroll
    for (int off = 32; off; off >>= 1) t2 += __shfl_down(t2, off, 64);
    __shared__ float sh[4];
    const int wave = tid >> 6, lane = tid & 63;
    if (lane == 0) sh[wave] = t2;
    __syncthreads();
    if (tid == 0) pT2[b] = sh[0] + sh[1] + sh[2] + sh[3];
}

// ---- kernel 4: all stats -> gates -> per-(n,c) affine coeffs A,B ---------
__global__ __launch_bounds__(256) void finalize_kernel(
    const float* __restrict__ S1, const float* __restrict__ S2,
    const float* __restrict__ partialT2,
    const float* __restrict__ weight, const float* __restrict__ bias,
    const float* __restrict__ gate_logits, const float* __restrict__ diag_proj,
    float* __restrict__ A, float* __restrict__ B)
{
    const int tid = threadIdx.x;
    __shared__ float sh_mu_b[CC], sh_rs_b[CC];
    __shared__ float sh_mu_g[NN * GROUPS], sh_rs_g[NN * GROUPS];
    __shared__ float sh_mu_l[NN], sh_rs_l[NN];
    __shared__ float sh_red1[4], sh_red2[4], sh_red3[4], sh_red4[4];
    __shared__ float sh_gate[3];

    const float inv_NHW  = 1.f / (float)NHW;
    const float inv_CHW  = 1.f / (float)CHW;
    const float inv_GHW  = 1.f / (float)GHW;
    const float inv_NCHW = 1.f / (float)NCHW;

    // ---- BN: per-channel stats (thread = channel) ----
    const int c = tid;
    float s1 = 0.f, s2 = 0.f;
    for (int n = 0; n < NN; ++n) { s1 += S1[n * CC + c]; s2 += S2[n * CC + c]; }
    const float mu_b  = s1 * inv_NHW;
    const float var_b = s2 * inv_NHW - mu_b * mu_b;
    sh_mu_b[c] = mu_b;
    sh_rs_b[c] = rsqrtf(var_b + EPSF);

    // ---- GN: per-(n,g) stats (thread = n*8+g) ----
    const int ng_n = tid >> 3, ng_g = tid & 7;
    float s1g = 0.f, s2g = 0.f;
    for (int cc = 0; cc < CPG; ++cc) {
        const int idx = ng_n * CC + ng_g * CPG + cc;
        s1g += S1[idx]; s2g += S2[idx];
    }
    const float mu_g  = s1g * inv_GHW;
    const float var_g = s2g * inv_GHW - mu_g * mu_g;
    sh_mu_g[tid] = mu_g;
    sh_rs_g[tid] = rsqrtf(var_g + EPSF);

    // ---- LN: reduce GN sums over the 8 groups of each sample ----
    float s1l = s1g, s2l = s2g;
    #pragma unroll
    for (int off = 1; off < 8; off <<= 1) {
        s1l += __shfl_xor(s1l, off, 64);
        s2l += __shfl_xor(s2l, off, 64);
    }
    float var_l_contrib = 0.f;
    if (ng_g == 0) {
        const float mu_l  = s1l * inv_CHW;
        const float var_l = s2l * inv_CHW - mu_l * mu_l;
        sh_mu_l[ng_n] = mu_l;
        sh_rs_l[ng_n] = rsqrtf(var_l + EPSF);
        var_l_contrib = var_l;
    }

    // ---- T^2 partials for channel_var ----
    float t2p = 0.f;
    for (int i = tid; i < NPT2; i += 256) t2p += partialT2[i];

    // ---- combined block reductions ----
    float r1 = var_b, r2 = s2, r3 = var_l_contrib, r4 = t2p;
    #pragma unroll
    for (int off = 32; off; off >>= 1) {
        r1 += __shfl_down(r1, off, 64);
        r2 += __shfl_down(r2, off, 64);
        r3 += __shfl_down(r3, off, 64);
        r4 += __shfl_down(r4, off, 64);
    }
    const int wave = tid >> 6, lane = tid & 63;
    if (lane == 0) { sh_red1[wave] = r1; sh_red2[wave] = r2; sh_red3[wave] = r3; sh_red4[wave] = r4; }
    __syncthreads();
    if (tid == 0) {
        const float sum_var_b = sh_red1[0] + sh_red1[1] + sh_red1[2] + sh_red1[3];
        const float total_x2  = sh_red2[0] + sh_red2[1] + sh_red2[2] + sh_red2[3];
        const float sum_var_l = sh_red3[0] + sh_red3[1] + sh_red3[2] + sh_red3[3];
        const float sum_T2    = sh_red4[0] + sh_red4[1] + sh_red4[2] + sh_red4[3];

        const float batch_var   = sum_var_b * (1.f / (float)CC);
        const float sample_var  = sum_var_l * (1.f / (float)NN);
        const float channel_var = total_x2 * inv_NCHW
                                - sum_T2 * inv_NHW * (1.f / ((float)CC * (float)CC));

        float desc[3];
        desc[0] = tanhf(logf(fmaxf(batch_var,   EPSF)));
        desc[1] = tanhf(logf(fmaxf(sample_var,  EPSF)));
        desc[2] = tanhf(logf(fmaxf(channel_var, EPSF)));

        float lg[3];
        #pragma unroll
        for (int i = 0; i < 3; ++i) {
            lg[i] = gate_logits[i] + diag_proj[i*3+0]*desc[0]
                                   + diag_proj[i*3+1]*desc[1]
                                   + diag_proj[i*3+2]*desc[2];
        }
        const float m = fmaxf(lg[0], fmaxf(lg[1], lg[2]));
        const float e0 = expf(lg[0]-m), e1 = expf(lg[1]-m), e2 = expf(lg[2]-m);
        const float inv = 1.f / (e0 + e1 + e2);
        sh_gate[0] = e0 * inv; sh_gate[1] = e1 * inv; sh_gate[2] = e2 * inv;
    }
    __syncthreads();

    // ---- per-(n,c) affine coefficients ----
    const float g0 = sh_gate[0], g1 = sh_gate[1], g2 = sh_gate[2];
    for (int i = tid; i < NN * CC; i += 256) {
        const int n = i >> 8, ch = i & 255, g = ch >> 5;
        const float w = weight[ch], bi = bias[ch];
        const float rb = sh_rs_b[ch], rl = sh_rs_l[n], rg = sh_rs_g[n*8+g];
        const float mb = sh_mu_b[ch], ml = sh_mu_l[n], mg = sh_mu_g[n*8+g];
        const float scale = g0*rb + g1*rl + g2*rg;
        const float offs  = g0*mb*rb + g1*ml*rl + g2*mg*rg;
        A[i] = w * scale;
        B[i] = bi - w * offs;
    }
}

// ---- kernel 5: y = x*A[nc] + B[nc], one block per (n,c) plane ------------
__global__ __launch_bounds__(256) void apply_kernel(
    const float4* __restrict__ x4, const float* __restrict__ A,
    const float* __restrict__ B, float4* __restrict__ y4)
{
    const int nc = blockIdx.x;
    const float a = A[nc], b = B[nc];
    const float4* xp = x4 + (size_t)nc * HW4;
    float4* yp = y4 + (size_t)nc * HW4;
    for (int i = threadIdx.x; i < HW4; i += 256) {
        float4 v = xp[i];
        v.x = fmaf(v.x, a, b);
        v.y = fmaf(v.y, a, b);
        v.z = fmaf(v.z, a, b);
        v.w = fmaf(v.w, a, b);
        yp[i] = v;
    }
}

extern "C" void kernel_launch(void* const* d_in, const int* in_sizes, int n_in,
                              void* d_out, int out_size, void* d_ws, size_t ws_size,
                              hipStream_t stream) {
    const float* x           = (const float*)d_in[0];
    const float* weight      = (const float*)d_in[1];
    const float* bias        = (const float*)d_in[2];
    const float* gate_logits = (const float*)d_in[3];
    const float* diag_proj   = (const float*)d_in[4];
    float* out = (float*)d_out;

    float* ws  = (float*)d_ws;
    float* S1  = ws;                 // 8192
    float* S2  = ws + 8192;          // 8192
    float* A   = ws + 16384;         // 8192
    float* B   = ws + 24576;         // 8192
    float* pT2 = ws + 32768;         // 416 (pad to 512)
    float* pT  = ws + 33280;         // CGS*NN*PCHUNK*256 = 212992

    plane_stats_kernel<<<NN * 64, 256, 0, stream>>>((const float4*)x, S1, S2);
    chansum_kernel<<<CGS * NN * PCHUNK, 256, 0, stream>>>(x, pT);
    combine_kernel<<<NN * PCHUNK, 256, 0, stream>>>(pT, pT2);
    finalize_kernel<<<1, 256, 0, stream>>>(S1, S2, pT2, weight, bias,
                                           gate_logits, diag_proj, A, B);
    apply_kernel<<<NN * CC, 256, 0, stream>>>((const float4*)x, A, B, (float4*)out);
}